// Round 8
// baseline (179.179 us; speedup 1.0000x reference)
//
#include <hip/hip_runtime.h>
#include <hip/hip_bf16.h>
#include <stdint.h>

// Problem constants (N,C,H,W = 4,128,64,64)
#define NB 4
#define CH 128
#define LL 4096   // H*W

typedef __attribute__((ext_vector_type(8))) short short8;   // 8 bf16 MFMA A/B frag
typedef __attribute__((ext_vector_type(4))) short short4b;  // 4 bf16 (8B)
typedef __attribute__((ext_vector_type(4))) float floatx4;  // 16x16 C/D frag
typedef __attribute__((ext_vector_type(16))) float floatx16; // 32x32 C/D frag

// Frag-major layout (verified R9-R13): element (row r, k) of 16-wide tile t:
//   t*2048 + (k>>5)*512 + ((k>>3)&3)*128 + (r&15)*8 + (k&7)
//
// R15: XCD pinning (FETCH 39.7->14.9 MB, kept).
// R18: l-split co-residency (attn 73->63.6, kept).
// R20 lesson: attn_out is a robust local optimum at ~63µs — traffic -2.7x
//   (R2), occupancy x2 (R5), loads -40% (R7) all failed to beat it. FROZEN.
// R21 (this round): rowsum de-spill. Since R14 both rowsum variants carried
//   ~140 live VGPRs (kf[2][4] 64 + qA/qB ping-pong 64 + rs/addr) under a
//   hard 128 cap (1024-thr block / launch_bounds(512,4)) -> forced scratch
//   spill in the 32-iter inner loop — invisible (top-5 saturated by
//   attn_out) but ≈45-60µs of the stubborn ~94µs "rest". Fix: drop the
//   ping-pong arrays; load ONE q-tile per iteration (live ≈106 ✓). Latency
//   is hidden by TLP (4 waves/SIMD x 136cyc work > 300cyc L2 latency),
//   not by ILP-prefetch that doesn't fit the register budget.

static __device__ __forceinline__ short f2bf(float f) {
    uint32_t u = __float_as_uint(f);
    u += 0x7fffu + ((u >> 16) & 1u);
    return (short)(u >> 16);
}
static __device__ __forceinline__ float bf2f(short s) {
    return __uint_as_float(((uint32_t)(uint16_t)s) << 16);
}

// ---------------------------------------------------------------------------
// Kernel 0: W prep — Wq/Wk/Wv fp32 [o][c] -> bf16 frag-major A-layout
// (rows=o, k=c). K-scale folded into Wk. (unchanged)
// ---------------------------------------------------------------------------
__global__ __launch_bounds__(256) void wprep_kernel(
    const float* __restrict__ Wq, const float* __restrict__ Wk,
    const float* __restrict__ Wv, short* __restrict__ Wf)
{
    const int g = blockIdx.x * 256 + threadIdx.x;   // 0..49151
    const int mat = g >> 14;
    const int rem = g & 16383;
    const int o   = rem >> 7;
    const int c   = rem & 127;
    const float* W = (mat == 0) ? Wq : (mat == 1) ? Wk : Wv;
    float v = W[o * CH + c];
    if (mat == 1) v *= 0.08838834764831845f;
    Wf[(size_t)mat * 16384 + (o >> 4) * 2048 + (c >> 5) * 512
       + ((c >> 3) & 3) * 128 + (o & 15) * 8 + (c & 7)] = f2bf(v);
}

// ---------------------------------------------------------------------------
// Kernel 1: QKV projection via MFMA (R12-proven structure, unchanged).
// Outputs Qf/Kf frag-major, Vp panel [n][l>>4][c][l&15].
// grid = 512 blocks x 256 thr. XCD-pinned block remap.
// ---------------------------------------------------------------------------
__global__ __launch_bounds__(256) void proj_kernel(
    const float* __restrict__ x, const short* __restrict__ Wf,
    const float* __restrict__ bq, const float* __restrict__ bk,
    const float* __restrict__ bv,
    short* __restrict__ Qf, short* __restrict__ Kf, short* __restrict__ Vp)
{
    const int i    = blockIdx.x;
    const int n    = (i >> 1) & 3;            // XCD pair {2n,2n+1}
    const int lt   = ((i >> 3) << 1) | (i & 1); // l-tile of 32 (0..127)
    const int l0   = lt << 5;
    const int tid  = threadIdx.x;
    const int wave = tid >> 6;        // 0..3
    const int lane = tid & 63;
    const int quad = lane >> 4;
    const int mc   = lane & 15;

    __shared__ short Xb[32][136];     // [l][c] bf16, +8 pad (8.7 KB)

    {
        const int sl = tid & 31;      // l
        const int cg = tid >> 5;      // c-group of 16 (0..7)
        const float* xp = x + ((size_t)n * CH + cg * 16) * LL + l0 + sl;
        short8 buf;
        #pragma unroll
        for (int i2 = 0; i2 < 16; ++i2) {
            buf[i2 & 7] = f2bf(xp[(size_t)i2 * LL]);
            if ((i2 & 7) == 7)
                *(short8*)(void*)&Xb[sl][cg * 16 + (i2 & 8)] = buf;
        }
    }
    __syncthreads();

    const int lt2 = wave >> 1;        // l-subtile of 16
    const int oh  = wave & 1;         // o-half (4 o-tiles)
    const int gt  = lt * 2 + lt2;     // global 16-l tile index

    short8 xf[4];                     // B-frags: B[k=c][col=l]
    #pragma unroll
    for (int s = 0; s < 4; ++s)
        xf[s] = *(const short8*)(const void*)&Xb[lt2 * 16 + mc][32 * s + quad * 8];

    const size_t obase = ((size_t)n * 256 + gt) * 2048;
    const float scale = 0.08838834764831845f;  // 1/sqrt(128)

    #pragma unroll
    for (int mat = 0; mat < 3; ++mat) {
        const short* Wm = Wf + (size_t)mat * 16384;
        const float* bb = (mat == 0) ? bq : (mat == 1) ? bk : bv;
        const float bscale = (mat == 1) ? scale : 1.0f;
        #pragma unroll
        for (int ot = oh * 4; ot < oh * 4 + 4; ++ot) {
            floatx4 acc = {0.f, 0.f, 0.f, 0.f};
            #pragma unroll
            for (int s = 0; s < 4; ++s)
                acc = __builtin_amdgcn_mfma_f32_16x16x32_bf16(
                    *(const short8*)(const void*)(Wm + ot * 2048 + s * 512 + lane * 8),
                    xf[s], acc, 0, 0, 0);
            const int c0 = ot * 16 + 4 * quad;
            if (mat < 2) {
                short4b pv;
                #pragma unroll
                for (int r = 0; r < 4; ++r)
                    pv[r] = f2bf(acc[r] + bb[c0 + r] * bscale);
                short* dst = ((mat == 0) ? Qf : Kf) + obase
                           + (c0 >> 5) * 512 + ((c0 >> 3) & 3) * 128
                           + mc * 8 + (c0 & 7);
                *(short4b*)(void*)dst = pv;
            } else {
                #pragma unroll
                for (int r = 0; r < 4; ++r)
                    Vp[obase + (c0 + r) * 16 + mc] = f2bf(acc[r] + bb[c0 + r]);
            }
        }
    }
}

// ---------------------------------------------------------------------------
// Kernel 2 (R21): softmax denominators -> rcpD[n][l]. NO-SPILL form.
// 256 blocks x 1024 thr (4 waves/SIMD); block = 4 K-tiles; wave (mw,th):
// m-eighth x K-tile pair, kf[2][4] resident (64 regs), ONE q-tile per
// iteration (16 regs transient) -> live ~106 < 128 cap. No ping-pong
// arrays (they forced ~140 live -> per-iteration scratch spill since R14).
// ---------------------------------------------------------------------------
__global__ __launch_bounds__(1024) void rowsum_kernel(
    const short* __restrict__ Qf, const short* __restrict__ Kf,
    float* __restrict__ Dv)
{
    const int i    = blockIdx.x;         // 256 blocks
    const int n    = (i >> 1) & 3;       // XCD pair {2n,2n+1}
    const int tq   = ((i >> 3) << 1) | (i & 1);  // 64-l group (0..63)
    const int tid  = threadIdx.x;
    const int wave = tid >> 6;           // 0..15
    const int lane = tid & 63;
    const int quad = lane >> 4;
    const int mc   = lane & 15;
    const int mw   = wave & 7;           // m-eighth (512 m = 32 q-tiles)
    const int th   = wave >> 3;          // K-tile half (2 of the 4 tiles)

    __shared__ float Db[16][32];         // per-wave partial D (2 KB)

    const short* Kb = Kf + ((size_t)n * 256 + tq * 4 + th * 2) * 2048 + lane * 8;
    short8 kf[2][4];
    #pragma unroll
    for (int t = 0; t < 2; ++t)
        #pragma unroll
        for (int s = 0; s < 4; ++s)
            kf[t][s] = *(const short8*)(const void*)(Kb + t * 2048 + s * 512);

    const short* Qn = Qf + (size_t)n * 524288 + (size_t)mw * 32 * 2048 + lane * 8;
    float rs[2][4] = {{0.f, 0.f, 0.f, 0.f}, {0.f, 0.f, 0.f, 0.f}};

    for (int it = 0; it < 32; ++it) {
        short8 q[4];
        #pragma unroll
        for (int s = 0; s < 4; ++s)
            q[s] = *(const short8*)(const void*)(
                Qn + (size_t)it * 2048 + s * 512);
        floatx4 a0 = {0.f, 0.f, 0.f, 0.f};
        floatx4 a1 = {0.f, 0.f, 0.f, 0.f};
        #pragma unroll
        for (int s = 0; s < 4; ++s) {
            a0 = __builtin_amdgcn_mfma_f32_16x16x32_bf16(kf[0][s], q[s], a0, 0, 0, 0);
            a1 = __builtin_amdgcn_mfma_f32_16x16x32_bf16(kf[1][s], q[s], a1, 0, 0, 0);
        }
        #pragma unroll
        for (int r = 0; r < 4; ++r) {
            rs[0][r] += __expf(a0[r]);
            rs[1][r] += __expf(a1[r]);
        }
    }

    // reduce over m within wave (cols live in mc lanes), then across 8 m-waves
    #pragma unroll
    for (int t = 0; t < 2; ++t)
        #pragma unroll
        for (int r = 0; r < 4; ++r) {
            float v = rs[t][r];
            v += __shfl_xor(v, 1);
            v += __shfl_xor(v, 2);
            v += __shfl_xor(v, 4);
            v += __shfl_xor(v, 8);
            if (mc == 0) Db[wave][t * 16 + quad * 4 + r] = v;
        }
    __syncthreads();
    if (tid < 64) {
        const int lh = tid >> 5, lr = tid & 31;
        float s = 0.f;
        #pragma unroll
        for (int m = 0; m < 8; ++m) s += Db[lh * 8 + m][lr];
        Dv[(size_t)n * 4096 + tq * 64 + tid] = 1.0f / s;
    }
}

// ---------------------------------------------------------------------------
// Kernel 3 (R5-frozen): partial O over an l-half.
// grid 512 = {n, m-block 64, l-half} x 512 thr (8 waves), 2 blocks/CU.
// 8 steps of 256 l; phase A: wave w -> l-tiles 2w,2w+1 (Q per-step from
// L2-hot Qf); phase B: wave (ct,mh) -> full 256-l sum, single acc.
// P stride 260 (2-way banks = free; 0 conflicts measured R6/R7).
// Writes partial O f32 to Po[lh][n][c][m].
// ---------------------------------------------------------------------------
__global__ __launch_bounds__(512, 4) void attn_out_kernel(
    const short* __restrict__ Qf, const short* __restrict__ Kf,
    const short* __restrict__ Vp, const float* __restrict__ Dv,
    float* __restrict__ Po)
{
    const int i    = blockIdx.x;
    const int n    = (i >> 1) & 3;               // XCD pair {2n,2n+1}
    const int j    = ((i >> 3) << 1) | (i & 1);  // 0..127
    const int lh   = j >> 6;                     // l-half
    const int mb   = j & 63;                     // m-block (0..63)
    const int m0   = mb << 6;
    const int tid  = threadIdx.x;
    const int wave = tid >> 6;          // 0..7
    const int lane = tid & 63;
    const int quad = lane >> 4;
    const int mc   = lane & 15;
    const int l32  = lane & 31;
    const int h    = lane >> 5;
    const int ct   = wave & 3;          // phase B c-tile (32 channels)
    const int mh   = wave >> 2;         // phase B m-half (32 cols)

    __shared__ short P[2][64][260];     // dbuf [m][l-local 256 +4] (65 KB)

    const short* Qn  = Qf + (size_t)n * 524288;
    const short* Kn  = Kf + (size_t)n * 524288;
    const short* Vpn = Vp + (size_t)n * 524288;
    const float* Dn  = Dv + (size_t)n * 4096;
    const int tile0  = lh * 128;        // first 16-l tile of this half

    floatx16 acc;
    #pragma unroll
    for (int r = 0; r < 16; ++r) acc[r] = 0.f;

    for (int t = 0; t < 8; ++t) {
        const int p = t & 1;

        // ---- phase A: wave w -> l-tiles {2w, 2w+1} of step t, 64 m ----
        {
            const int tb = tile0 + t * 16 + 2 * wave;
            short8 kfr[2][4];
            #pragma unroll
            for (int jj = 0; jj < 2; ++jj)
                #pragma unroll
                for (int s = 0; s < 4; ++s)
                    kfr[jj][s] = *(const short8*)(const void*)(
                        Kn + (size_t)(tb + jj) * 2048 + s * 512 + lane * 8);
            floatx4 dr[2];
            #pragma unroll
            for (int jj = 0; jj < 2; ++jj)
                dr[jj] = *(const floatx4*)(const void*)(
                    Dn + (tb + jj) * 16 + quad * 4);

            #pragma unroll
            for (int mst = 0; mst < 4; ++mst) {
                short8 qt[4];
                #pragma unroll
                for (int s = 0; s < 4; ++s)
                    qt[s] = *(const short8*)(const void*)(
                        Qn + (size_t)((m0 >> 4) + mst) * 2048 + s * 512 + lane * 8);
                floatx4 sa0 = {0.f, 0.f, 0.f, 0.f};
                floatx4 sa1 = {0.f, 0.f, 0.f, 0.f};
                #pragma unroll
                for (int s = 0; s < 4; ++s) {
                    sa0 = __builtin_amdgcn_mfma_f32_16x16x32_bf16(kfr[0][s], qt[s], sa0, 0, 0, 0);
                    sa1 = __builtin_amdgcn_mfma_f32_16x16x32_bf16(kfr[1][s], qt[s], sa1, 0, 0, 0);
                }
                short4b pv0, pv1;
                #pragma unroll
                for (int r = 0; r < 4; ++r) {
                    pv0[r] = f2bf(__expf(sa0[r]) * dr[0][r]);
                    pv1[r] = f2bf(__expf(sa1[r]) * dr[1][r]);
                }
                // C-layout (row=l=4q+r, col=m=mc) -> P[m][l-local]
                *(short4b*)(void*)&P[p][16 * mst + mc][32 * wave + quad * 4] = pv0;
                *(short4b*)(void*)&P[p][16 * mst + mc][32 * wave + 16 + quad * 4] = pv1;
            }
        }
        __syncthreads();   // only barrier: P[p] visible

        // ---- phase B: wave (ct,mh): full 256-l sum, 16 chunks ----
        #pragma unroll
        for (int kc = 0; kc < 16; ++kc) {
            const short8 vf = *(const short8*)(const void*)(
                Vpn + (size_t)(tile0 + t * 16 + kc) * 2048
                    + (32 * ct + l32) * 16 + 8 * h);
            const short8 pf = *(const short8*)(const void*)&P[p][32 * mh + l32][16 * kc + 8 * h];
            acc = __builtin_amdgcn_mfma_f32_32x32x16_bf16(vf, pf, acc, 0, 0, 0);
        }
        // no trailing barrier: next step writes P[p^1]
    }

    // ---- epilogue: write partial O (f32), 32x32 C-layout ----
    float* Pon = Po + (size_t)(lh * 4 + n) * 524288;  // [lh][n][c][m]
    #pragma unroll
    for (int r = 0; r < 16; ++r) {
        const int c = 32 * ct + (r & 3) + 8 * (r >> 2) + 4 * h;
        const int m = m0 + 32 * mh + l32;
        Pon[(size_t)c * LL + m] = acc[r];
    }
}

// ---------------------------------------------------------------------------
// Kernel 4: out = x + Po[0] + Po[1].  524288 float4s, 1 per thread.
// ---------------------------------------------------------------------------
__global__ __launch_bounds__(256) void combine_kernel(
    const float* __restrict__ x, const float* __restrict__ Po,
    float* __restrict__ out)
{
    const size_t k = (size_t)blockIdx.x * 256 + threadIdx.x;  // float4 idx
    const floatx4 a = *(const floatx4*)(const void*)(x + 4 * k);
    const floatx4 b = *(const floatx4*)(const void*)(Po + 4 * k);
    const floatx4 c = *(const floatx4*)(const void*)(Po + 2097152 + 4 * k);
    floatx4 o;
    #pragma unroll
    for (int r = 0; r < 4; ++r) o[r] = a[r] + b[r] + c[r];
    *(floatx4*)(void*)(out + 4 * k) = o;
}

// ---------------------------------------------------------------------------
extern "C" void kernel_launch(void* const* d_in, const int* in_sizes, int n_in,
                              void* d_out, int out_size, void* d_ws, size_t ws_size,
                              hipStream_t stream) {
    (void)in_sizes; (void)n_in; (void)out_size; (void)ws_size;
    const float* x  = (const float*)d_in[0];
    const float* Wq = (const float*)d_in[1];
    const float* bq = (const float*)d_in[2];
    const float* Wk = (const float*)d_in[3];
    const float* bk = (const float*)d_in[4];
    const float* Wv = (const float*)d_in[5];
    const float* bv = (const float*)d_in[6];
    float* out = (float*)d_out;

    char* ws = (char*)d_ws;
    // ws: Qf 4MB | Kf 4MB | Vp 4MB | Dv 64KB | Wf 96KB+pad | Po 16MB (~33MB)
    short* Qf = (short*)(ws);
    short* Kf = (short*)(ws + 4194304);
    short* Vp = (short*)(ws + 8388608);
    float* Dv = (float*)(ws + 12582912);
    short* Wf = (short*)(ws + 16777216);
    float* Po = (float*)(ws + 16908288);

    wprep_kernel<<<192, 256, 0, stream>>>(Wq, Wk, Wv, Wf);
    proj_kernel<<<512, 256, 0, stream>>>(x, Wf, bq, bk, bv, Qf, Kf, Vp);
    rowsum_kernel<<<256, 1024, 0, stream>>>(Qf, Kf, Dv);
    attn_out_kernel<<<512, 512, 0, stream>>>(Qf, Kf, Vp, Dv, Po);
    combine_kernel<<<2048, 256, 0, stream>>>(x, Po, out);
}

// Round 9
// 160.960 us; speedup vs baseline: 1.1132x; 1.1132x over previous
//
#include <hip/hip_runtime.h>
#include <hip/hip_bf16.h>
#include <stdint.h>

// Problem constants (N,C,H,W = 4,128,64,64)
#define NB 4
#define CH 128
#define LL 4096   // H*W

typedef __attribute__((ext_vector_type(8))) short short8;   // 8 bf16 MFMA A/B frag (4 VGPR)
typedef __attribute__((ext_vector_type(4))) short short4b;  // 4 bf16 (8B)
typedef __attribute__((ext_vector_type(4))) float floatx4;  // 16x16 C/D frag
typedef __attribute__((ext_vector_type(16))) float floatx16; // 32x32 C/D frag

// Frag-major layout (verified R9-R13): element (row r, k) of 16-wide tile t:
//   t*2048 + (k>>5)*512 + ((k>>3)&3)*128 + (r&15)*8 + (k&7)
//
// R15: XCD pinning (FETCH 39.7->14.9 MB, kept).
// R18: l-split co-residency (attn 73->63.6, kept).
// R22 (this round):
//   - attn_out restored to R5 EXACTLY: P row stride MUST be 264 shorts
//     (528 B = multiple of 16). R8's 260 (520 B = 8 mod 16) misaligned
//     every odd-row short8 P-read -> ds_read_b128 split -> 63.6->86.5 µs
//     despite conflicts 1.05M->0. Alignment >> bank conflicts here.
//   - rowsum kept in R21 no-ping-pong form (register audit: short8 = 4
//     VGPR, so R14 never spilled; variants all within ±1.5 µs — frozen).
//   - combine_kernel XCD-pinned: Po[·][n] was written by XCD pair
//     {2n,2n+1}; pinning the reader blocks to the same pair converts
//     ~32 MB of L3 reads into pair-L2 hits.

static __device__ __forceinline__ short f2bf(float f) {
    uint32_t u = __float_as_uint(f);
    u += 0x7fffu + ((u >> 16) & 1u);
    return (short)(u >> 16);
}
static __device__ __forceinline__ float bf2f(short s) {
    return __uint_as_float(((uint32_t)(uint16_t)s) << 16);
}

// ---------------------------------------------------------------------------
// Kernel 0: W prep — Wq/Wk/Wv fp32 [o][c] -> bf16 frag-major A-layout
// (rows=o, k=c). K-scale folded into Wk. (unchanged)
// ---------------------------------------------------------------------------
__global__ __launch_bounds__(256) void wprep_kernel(
    const float* __restrict__ Wq, const float* __restrict__ Wk,
    const float* __restrict__ Wv, short* __restrict__ Wf)
{
    const int g = blockIdx.x * 256 + threadIdx.x;   // 0..49151
    const int mat = g >> 14;
    const int rem = g & 16383;
    const int o   = rem >> 7;
    const int c   = rem & 127;
    const float* W = (mat == 0) ? Wq : (mat == 1) ? Wk : Wv;
    float v = W[o * CH + c];
    if (mat == 1) v *= 0.08838834764831845f;
    Wf[(size_t)mat * 16384 + (o >> 4) * 2048 + (c >> 5) * 512
       + ((c >> 3) & 3) * 128 + (o & 15) * 8 + (c & 7)] = f2bf(v);
}

// ---------------------------------------------------------------------------
// Kernel 1: QKV projection via MFMA (R12-proven structure, unchanged).
// Outputs Qf/Kf frag-major, Vp panel [n][l>>4][c][l&15].
// grid = 512 blocks x 256 thr. XCD-pinned block remap.
// ---------------------------------------------------------------------------
__global__ __launch_bounds__(256) void proj_kernel(
    const float* __restrict__ x, const short* __restrict__ Wf,
    const float* __restrict__ bq, const float* __restrict__ bk,
    const float* __restrict__ bv,
    short* __restrict__ Qf, short* __restrict__ Kf, short* __restrict__ Vp)
{
    const int i    = blockIdx.x;
    const int n    = (i >> 1) & 3;            // XCD pair {2n,2n+1}
    const int lt   = ((i >> 3) << 1) | (i & 1); // l-tile of 32 (0..127)
    const int l0   = lt << 5;
    const int tid  = threadIdx.x;
    const int wave = tid >> 6;        // 0..3
    const int lane = tid & 63;
    const int quad = lane >> 4;
    const int mc   = lane & 15;

    __shared__ short Xb[32][136];     // [l][c] bf16, +8 pad (8.7 KB)

    {
        const int sl = tid & 31;      // l
        const int cg = tid >> 5;      // c-group of 16 (0..7)
        const float* xp = x + ((size_t)n * CH + cg * 16) * LL + l0 + sl;
        short8 buf;
        #pragma unroll
        for (int i2 = 0; i2 < 16; ++i2) {
            buf[i2 & 7] = f2bf(xp[(size_t)i2 * LL]);
            if ((i2 & 7) == 7)
                *(short8*)(void*)&Xb[sl][cg * 16 + (i2 & 8)] = buf;
        }
    }
    __syncthreads();

    const int lt2 = wave >> 1;        // l-subtile of 16
    const int oh  = wave & 1;         // o-half (4 o-tiles)
    const int gt  = lt * 2 + lt2;     // global 16-l tile index

    short8 xf[4];                     // B-frags: B[k=c][col=l]
    #pragma unroll
    for (int s = 0; s < 4; ++s)
        xf[s] = *(const short8*)(const void*)&Xb[lt2 * 16 + mc][32 * s + quad * 8];

    const size_t obase = ((size_t)n * 256 + gt) * 2048;
    const float scale = 0.08838834764831845f;  // 1/sqrt(128)

    #pragma unroll
    for (int mat = 0; mat < 3; ++mat) {
        const short* Wm = Wf + (size_t)mat * 16384;
        const float* bb = (mat == 0) ? bq : (mat == 1) ? bk : bv;
        const float bscale = (mat == 1) ? scale : 1.0f;
        #pragma unroll
        for (int ot = oh * 4; ot < oh * 4 + 4; ++ot) {
            floatx4 acc = {0.f, 0.f, 0.f, 0.f};
            #pragma unroll
            for (int s = 0; s < 4; ++s)
                acc = __builtin_amdgcn_mfma_f32_16x16x32_bf16(
                    *(const short8*)(const void*)(Wm + ot * 2048 + s * 512 + lane * 8),
                    xf[s], acc, 0, 0, 0);
            const int c0 = ot * 16 + 4 * quad;
            if (mat < 2) {
                short4b pv;
                #pragma unroll
                for (int r = 0; r < 4; ++r)
                    pv[r] = f2bf(acc[r] + bb[c0 + r] * bscale);
                short* dst = ((mat == 0) ? Qf : Kf) + obase
                           + (c0 >> 5) * 512 + ((c0 >> 3) & 3) * 128
                           + mc * 8 + (c0 & 7);
                *(short4b*)(void*)dst = pv;
            } else {
                #pragma unroll
                for (int r = 0; r < 4; ++r)
                    Vp[obase + (c0 + r) * 16 + mc] = f2bf(acc[r] + bb[c0 + r]);
            }
        }
    }
}

// ---------------------------------------------------------------------------
// Kernel 2 (R21, frozen): softmax denominators -> rcpD[n][l].
// 256 blocks x 1024 thr; block = 4 K-tiles; wave (mw,th): m-eighth x
// K-tile pair, kf[2][4] resident, one q-tile per iteration.
// ---------------------------------------------------------------------------
__global__ __launch_bounds__(1024) void rowsum_kernel(
    const short* __restrict__ Qf, const short* __restrict__ Kf,
    float* __restrict__ Dv)
{
    const int i    = blockIdx.x;         // 256 blocks
    const int n    = (i >> 1) & 3;       // XCD pair {2n,2n+1}
    const int tq   = ((i >> 3) << 1) | (i & 1);  // 64-l group (0..63)
    const int tid  = threadIdx.x;
    const int wave = tid >> 6;           // 0..15
    const int lane = tid & 63;
    const int quad = lane >> 4;
    const int mc   = lane & 15;
    const int mw   = wave & 7;           // m-eighth (512 m = 32 q-tiles)
    const int th   = wave >> 3;          // K-tile half (2 of the 4 tiles)

    __shared__ float Db[16][32];         // per-wave partial D (2 KB)

    const short* Kb = Kf + ((size_t)n * 256 + tq * 4 + th * 2) * 2048 + lane * 8;
    short8 kf[2][4];
    #pragma unroll
    for (int t = 0; t < 2; ++t)
        #pragma unroll
        for (int s = 0; s < 4; ++s)
            kf[t][s] = *(const short8*)(const void*)(Kb + t * 2048 + s * 512);

    const short* Qn = Qf + (size_t)n * 524288 + (size_t)mw * 32 * 2048 + lane * 8;
    float rs[2][4] = {{0.f, 0.f, 0.f, 0.f}, {0.f, 0.f, 0.f, 0.f}};

    for (int it = 0; it < 32; ++it) {
        short8 q[4];
        #pragma unroll
        for (int s = 0; s < 4; ++s)
            q[s] = *(const short8*)(const void*)(
                Qn + (size_t)it * 2048 + s * 512);
        floatx4 a0 = {0.f, 0.f, 0.f, 0.f};
        floatx4 a1 = {0.f, 0.f, 0.f, 0.f};
        #pragma unroll
        for (int s = 0; s < 4; ++s) {
            a0 = __builtin_amdgcn_mfma_f32_16x16x32_bf16(kf[0][s], q[s], a0, 0, 0, 0);
            a1 = __builtin_amdgcn_mfma_f32_16x16x32_bf16(kf[1][s], q[s], a1, 0, 0, 0);
        }
        #pragma unroll
        for (int r = 0; r < 4; ++r) {
            rs[0][r] += __expf(a0[r]);
            rs[1][r] += __expf(a1[r]);
        }
    }

    // reduce over m within wave (cols live in mc lanes), then across 8 m-waves
    #pragma unroll
    for (int t = 0; t < 2; ++t)
        #pragma unroll
        for (int r = 0; r < 4; ++r) {
            float v = rs[t][r];
            v += __shfl_xor(v, 1);
            v += __shfl_xor(v, 2);
            v += __shfl_xor(v, 4);
            v += __shfl_xor(v, 8);
            if (mc == 0) Db[wave][t * 16 + quad * 4 + r] = v;
        }
    __syncthreads();
    if (tid < 64) {
        const int lh = tid >> 5, lr = tid & 31;
        float s = 0.f;
        #pragma unroll
        for (int m = 0; m < 8; ++m) s += Db[lh * 8 + m][lr];
        Dv[(size_t)n * 4096 + tq * 64 + tid] = 1.0f / s;
    }
}

// ---------------------------------------------------------------------------
// Kernel 3 (R5 verbatim — the proven 63.6 µs form): partial O over l-half.
// grid 512 = {n, m-block 64, l-half} x 512 thr (8 waves), 2 blocks/CU.
// 8 steps of 256 l; phase A: wave w -> l-tiles 2w,2w+1 (Q per-step from
// L2-hot Qf); phase B: wave (ct,mh) -> full 256-l sum, single acc.
// P row stride 264 shorts (528 B — 16B-aligned rows; REQUIRED, see R22
// header note). Writes partial O f32 to Po[lh][n][c][m].
// ---------------------------------------------------------------------------
__global__ __launch_bounds__(512, 4) void attn_out_kernel(
    const short* __restrict__ Qf, const short* __restrict__ Kf,
    const short* __restrict__ Vp, const float* __restrict__ Dv,
    float* __restrict__ Po)
{
    const int i    = blockIdx.x;
    const int n    = (i >> 1) & 3;               // XCD pair {2n,2n+1}
    const int j    = ((i >> 3) << 1) | (i & 1);  // 0..127
    const int lh   = j >> 6;                     // l-half
    const int mb   = j & 63;                     // m-block (0..63)
    const int m0   = mb << 6;
    const int tid  = threadIdx.x;
    const int wave = tid >> 6;          // 0..7
    const int lane = tid & 63;
    const int quad = lane >> 4;
    const int mc   = lane & 15;
    const int l32  = lane & 31;
    const int h    = lane >> 5;
    const int ct   = wave & 3;          // phase B c-tile (32 channels)
    const int mh   = wave >> 2;         // phase B m-half (32 cols)

    __shared__ short P[2][64][264];     // dbuf [m][l-local 256 +8] (66 KB)

    const short* Qn  = Qf + (size_t)n * 524288;
    const short* Kn  = Kf + (size_t)n * 524288;
    const short* Vpn = Vp + (size_t)n * 524288;
    const float* Dn  = Dv + (size_t)n * 4096;
    const int tile0  = lh * 128;        // first 16-l tile of this half

    floatx16 acc;
    #pragma unroll
    for (int r = 0; r < 16; ++r) acc[r] = 0.f;

    for (int t = 0; t < 8; ++t) {
        const int p = t & 1;

        // ---- phase A: wave w -> l-tiles {2w, 2w+1} of step t, 64 m ----
        {
            const int tb = tile0 + t * 16 + 2 * wave;
            short8 kfr[2][4];
            #pragma unroll
            for (int jj = 0; jj < 2; ++jj)
                #pragma unroll
                for (int s = 0; s < 4; ++s)
                    kfr[jj][s] = *(const short8*)(const void*)(
                        Kn + (size_t)(tb + jj) * 2048 + s * 512 + lane * 8);
            floatx4 dr[2];
            #pragma unroll
            for (int jj = 0; jj < 2; ++jj)
                dr[jj] = *(const floatx4*)(const void*)(
                    Dn + (tb + jj) * 16 + quad * 4);

            #pragma unroll
            for (int mst = 0; mst < 4; ++mst) {
                short8 qt[4];
                #pragma unroll
                for (int s = 0; s < 4; ++s)
                    qt[s] = *(const short8*)(const void*)(
                        Qn + (size_t)((m0 >> 4) + mst) * 2048 + s * 512 + lane * 8);
                floatx4 sa0 = {0.f, 0.f, 0.f, 0.f};
                floatx4 sa1 = {0.f, 0.f, 0.f, 0.f};
                #pragma unroll
                for (int s = 0; s < 4; ++s) {
                    sa0 = __builtin_amdgcn_mfma_f32_16x16x32_bf16(kfr[0][s], qt[s], sa0, 0, 0, 0);
                    sa1 = __builtin_amdgcn_mfma_f32_16x16x32_bf16(kfr[1][s], qt[s], sa1, 0, 0, 0);
                }
                short4b pv0, pv1;
                #pragma unroll
                for (int r = 0; r < 4; ++r) {
                    pv0[r] = f2bf(__expf(sa0[r]) * dr[0][r]);
                    pv1[r] = f2bf(__expf(sa1[r]) * dr[1][r]);
                }
                // C-layout (row=l=4q+r, col=m=mc) -> P[m][l-local]
                *(short4b*)(void*)&P[p][16 * mst + mc][32 * wave + quad * 4] = pv0;
                *(short4b*)(void*)&P[p][16 * mst + mc][32 * wave + 16 + quad * 4] = pv1;
            }
        }
        __syncthreads();   // only barrier: P[p] visible

        // ---- phase B: wave (ct,mh): full 256-l sum, 16 chunks ----
        #pragma unroll
        for (int kc = 0; kc < 16; ++kc) {
            const short8 vf = *(const short8*)(const void*)(
                Vpn + (size_t)(tile0 + t * 16 + kc) * 2048
                    + (32 * ct + l32) * 16 + 8 * h);
            const short8 pf = *(const short8*)(const void*)&P[p][32 * mh + l32][16 * kc + 8 * h];
            acc = __builtin_amdgcn_mfma_f32_32x32x16_bf16(vf, pf, acc, 0, 0, 0);
        }
        // no trailing barrier: next step writes P[p^1]
    }

    // ---- epilogue: write partial O (f32), 32x32 C-layout ----
    float* Pon = Po + (size_t)(lh * 4 + n) * 524288;  // [lh][n][c][m]
    #pragma unroll
    for (int r = 0; r < 16; ++r) {
        const int c = 32 * ct + (r & 3) + 8 * (r >> 2) + 4 * h;
        const int m = m0 + 32 * mh + l32;
        Pon[(size_t)c * LL + m] = acc[r];
    }
}

// ---------------------------------------------------------------------------
// Kernel 4 (R22): out = x + Po[0] + Po[1], XCD-pinned.
// Po[lh][n] was written by XCD pair {2n,2n+1}; pin reader blocks to the
// same pair so Po reads hit pair-L2. Po[0] shares the flat [n][c][m]
// layout with out, so flat index = 4*k works for x, Po0, out directly.
// grid 2048 x 256 thr (1 float4/thread).
// ---------------------------------------------------------------------------
__global__ __launch_bounds__(256) void combine_kernel(
    const float* __restrict__ x, const float* __restrict__ Po,
    float* __restrict__ out)
{
    const int i = blockIdx.x;
    const int n = (i >> 1) & 3;                  // XCD pair {2n,2n+1}
    const int j = ((i >> 3) << 1) | (i & 1);     // 0..511 within n
    const size_t k = ((size_t)((n << 9) | j)) * 256 + threadIdx.x;  // float4 idx
    const floatx4 a = *(const floatx4*)(const void*)(x + 4 * k);
    const floatx4 b = *(const floatx4*)(const void*)(Po + 4 * k);
    const floatx4 c = *(const floatx4*)(const void*)(Po + 2097152 + 4 * k);
    floatx4 o;
    #pragma unroll
    for (int r = 0; r < 4; ++r) o[r] = a[r] + b[r] + c[r];
    *(floatx4*)(void*)(out + 4 * k) = o;
}

// ---------------------------------------------------------------------------
extern "C" void kernel_launch(void* const* d_in, const int* in_sizes, int n_in,
                              void* d_out, int out_size, void* d_ws, size_t ws_size,
                              hipStream_t stream) {
    (void)in_sizes; (void)n_in; (void)out_size; (void)ws_size;
    const float* x  = (const float*)d_in[0];
    const float* Wq = (const float*)d_in[1];
    const float* bq = (const float*)d_in[2];
    const float* Wk = (const float*)d_in[3];
    const float* bk = (const float*)d_in[4];
    const float* Wv = (const float*)d_in[5];
    const float* bv = (const float*)d_in[6];
    float* out = (float*)d_out;

    char* ws = (char*)d_ws;
    // ws: Qf 4MB | Kf 4MB | Vp 4MB | Dv 64KB | Wf 96KB+pad | Po 16MB (~33MB)
    short* Qf = (short*)(ws);
    short* Kf = (short*)(ws + 4194304);
    short* Vp = (short*)(ws + 8388608);
    float* Dv = (float*)(ws + 12582912);
    short* Wf = (short*)(ws + 16777216);
    float* Po = (float*)(ws + 16908288);

    wprep_kernel<<<192, 256, 0, stream>>>(Wq, Wk, Wv, Wf);
    proj_kernel<<<512, 256, 0, stream>>>(x, Wf, bq, bk, bv, Qf, Kf, Vp);
    rowsum_kernel<<<256, 1024, 0, stream>>>(Qf, Kf, Dv);
    attn_out_kernel<<<512, 512, 0, stream>>>(Qf, Kf, Vp, Dv, Po);
    combine_kernel<<<2048, 256, 0, stream>>>(x, Po, out);
}